// Round 2
// baseline (563.211 us; speedup 1.0000x reference)
//
#include <hip/hip_runtime.h>
#include <hip/hip_bf16.h>

// EulerIntegrator: B=4096, D=1024, R=256, steps=8, dt=0.01
// Persistent per-row-tile kernel: 256 blocks x 16 rows, all steps local.
// GEMM1: P[16x256] = v[16x1024] @ U   (bf16 MFMA 16x16x32)
// GEMM2: G[16x1024] = (P*P)[16x256] @ W
// Round 2: software-pipelined register rings for B-fragment loads (depth 4 / 8),
// full unroll, lgkm-only barriers so in-flight global loads survive phase edges.

#define BB 4096
#define DD 1024
#define RR 256
#define DT 0.01f

typedef __attribute__((ext_vector_type(8))) short short8;   // 8 bf16 = 4 VGPRs
typedef __attribute__((ext_vector_type(4))) float floatx4;  // MFMA acc

// s_waitcnt imm: vmcnt[3:0]|[15:14], expcnt[6:4], lgkmcnt[11:8]
// lgkmcnt(0) only, vmcnt/expcnt unconstrained:
#define BARRIER_LGKM() do { \
    __builtin_amdgcn_s_waitcnt(0xC07F); \
    __builtin_amdgcn_s_barrier(); \
} while (0)

static __device__ inline unsigned short f2bf(float f) {
    union { float f; unsigned int u; } c; c.f = f;
    unsigned int u = c.u;
    u += 0x7fffu + ((u >> 16) & 1u);   // round-to-nearest-even
    return (unsigned short)(u >> 16);
}

// Pack U [1024][256] and W [256][1024] (fp32 row-major) into bf16 MFMA
// B-fragment order: dst[(kt*NT + nt)*64 + lane] = 8 bf16, element j =
// M[kt*32 + (lane>>4)*8 + j][nt*16 + (lane&15)].
__global__ void pack_kernel(const float* __restrict__ U, const float* __restrict__ W,
                            short* __restrict__ Up, short* __restrict__ Wp) {
    int t = blockIdx.x * blockDim.x + threadIdx.x;  // 0..65535
    if (t < 32768) {
        int lane = t & 63;
        int nl = lane & 15, kq = lane >> 4;
        int idx = t >> 6;            // kt*16 + nt
        int nt = idx & 15, kt = idx >> 4;
        short8 o;
#pragma unroll
        for (int j = 0; j < 8; j++) {
            int k = kt * 32 + kq * 8 + j;
            int n = nt * 16 + nl;
            o[j] = (short)f2bf(U[k * RR + n]);
        }
        ((short8*)Up)[t] = o;
    } else {
        int t2 = t - 32768;
        int lane = t2 & 63;
        int nl = lane & 15, kq = lane >> 4;
        int idx = t2 >> 6;           // kt*64 + nt
        int nt = idx & 63, kt = idx >> 6;
        short8 o;
#pragma unroll
        for (int j = 0; j < 8; j++) {
            int k = kt * 32 + kq * 8 + j;
            int n = nt * 16 + nl;
            o[j] = (short)f2bf(W[k * DD + n]);
        }
        ((short8*)Wp)[t2] = o;
    }
}

__global__ __launch_bounds__(512, 2)
void euler_kernel(const float* __restrict__ x0,
                  const float* __restrict__ v0,
                  const float* __restrict__ force,
                  const short8* __restrict__ Up,
                  const short8* __restrict__ Wp,
                  const int* __restrict__ steps_p,
                  float* __restrict__ out) {
    __shared__ __align__(16) short v_lds[16][1032];   // 33.0 KB, bf16 v tile
    __shared__ __align__(16) short p2_lds[16][264];   //  8.4 KB, bf16 p^2 tile

    const int tid  = threadIdx.x;
    const int wave = tid >> 6;          // 0..7
    const int lane = tid & 63;
    const int nl   = lane & 15;         // M (A) / N (B) / col (C)
    const int quad = lane >> 4;         // 0..3
    const int row0 = blockIdx.x * 16;

    const int steps = steps_p[0];

    // Ownership (matches MFMA C/D layout of GEMM2, 8 tiles/wave):
    // element (tt, r): row = 4*quad + r, col = 128*wave + 16*tt + nl
    float v_reg[8][4], f_reg[8][4], sv[8][4];

#pragma unroll
    for (int tt = 0; tt < 8; tt++) {
        int col = 128 * wave + 16 * tt + nl;
#pragma unroll
        for (int r = 0; r < 4; r++) {
            int row = 4 * quad + r;
            long g = (long)(row0 + row) * DD + col;
            v_reg[tt][r] = v0[g];
            f_reg[tt][r] = force[g];
            sv[tt][r] = 0.0f;
            v_lds[row][col] = (short)f2bf(v_reg[tt][r]);
        }
    }

    // -------- GEMM1 B-ring (depth 4) and GEMM2 B-ring (depth 8), regs.
    short8 b0r[4], b1r[4], br[8];

    // GEMM1 prologue for step 0 (before the barrier: loads only touch regs).
#pragma unroll
    for (int i = 0; i < 4; i++) {
        b0r[i] = Up[(i * 16 + 2 * wave    ) * 64 + lane];
        b1r[i] = Up[(i * 16 + 2 * wave + 1) * 64 + lane];
    }

    BARRIER_LGKM();

    for (int s = 0; s < steps; s++) {
        // ---------------- GEMM1: P = v @ U ; wave computes nt = 2w, 2w+1
        floatx4 acc0 = {0.f, 0.f, 0.f, 0.f};
        floatx4 acc1 = {0.f, 0.f, 0.f, 0.f};
#pragma unroll
        for (int kt = 0; kt < 32; kt++) {
            short8 a = *(const short8*)&v_lds[nl][kt * 32 + quad * 8];
            acc0 = __builtin_amdgcn_mfma_f32_16x16x32_bf16(a, b0r[kt & 3], acc0, 0, 0, 0);
            acc1 = __builtin_amdgcn_mfma_f32_16x16x32_bf16(a, b1r[kt & 3], acc1, 0, 0, 0);
            if (kt < 28) {
                b0r[kt & 3] = Up[((kt + 4) * 16 + 2 * wave    ) * 64 + lane];
                b1r[kt & 3] = Up[((kt + 4) * 16 + 2 * wave + 1) * 64 + lane];
            }
        }

        // GEMM2 prologue (kt=0, tt=0..7) — in flight across the p2 barrier.
#pragma unroll
        for (int j = 0; j < 8; j++)
            br[j] = Wp[(8 * wave + j) * 64 + lane];

        // p^2 epilogue -> LDS (D layout: row = 4*quad + r, col = nt*16 + nl)
#pragma unroll
        for (int r = 0; r < 4; r++) {
            int row = 4 * quad + r;
            float p0 = acc0[r], p1 = acc1[r];
            p2_lds[row][32 * wave + nl]      = (short)f2bf(p0 * p0);
            p2_lds[row][32 * wave + 16 + nl] = (short)f2bf(p1 * p1);
        }
        BARRIER_LGKM();

        // ---------------- GEMM2: G = p2 @ W ; wave computes nt = 8w + tt
        floatx4 acc[8];
#pragma unroll
        for (int tt = 0; tt < 8; tt++) acc[tt] = (floatx4){0.f, 0.f, 0.f, 0.f};
        short8 a2;
#pragma unroll
        for (int f = 0; f < 64; f++) {
            int kt = f >> 3, tt = f & 7;
            if (tt == 0)
                a2 = *(const short8*)&p2_lds[nl][kt * 32 + quad * 8];
            acc[tt] = __builtin_amdgcn_mfma_f32_16x16x32_bf16(a2, br[tt], acc[tt], 0, 0, 0);
            if (f < 56)
                br[tt] = Wp[((kt + 1) * 64 + 8 * wave + tt) * 64 + lane];
        }

        // GEMM1 prologue for next step — in flight across the v barrier.
#pragma unroll
        for (int i = 0; i < 4; i++) {
            b0r[i] = Up[(i * 16 + 2 * wave    ) * 64 + lane];
            b1r[i] = Up[(i * 16 + 2 * wave + 1) * 64 + lane];
        }

        // Euler update epilogue, refresh bf16 v in LDS
#pragma unroll
        for (int tt = 0; tt < 8; tt++) {
            int col = 128 * wave + 16 * tt + nl;
#pragma unroll
            for (int r = 0; r < 4; r++) {
                int row = 4 * quad + r;
                float gma = acc[tt][r];
                sv[tt][r] += v_reg[tt][r];                       // x accumulates pre-update v
                v_reg[tt][r] += DT * (f_reg[tt][r] - gma);
                v_lds[row][col] = (short)f2bf(v_reg[tt][r]);
            }
        }
        BARRIER_LGKM();
    }

    // outputs: [cx | cv], cx = x0 + dt * sum(v_t)
#pragma unroll
    for (int tt = 0; tt < 8; tt++) {
        int col = 128 * wave + 16 * tt + nl;
#pragma unroll
        for (int r = 0; r < 4; r++) {
            int row = 4 * quad + r;
            long g = (long)(row0 + row) * DD + col;
            out[g] = x0[g] + DT * sv[tt][r];
            out[(long)BB * DD + g] = v_reg[tt][r];
        }
    }
}

extern "C" void kernel_launch(void* const* d_in, const int* in_sizes, int n_in,
                              void* d_out, int out_size, void* d_ws, size_t ws_size,
                              hipStream_t stream) {
    const float* x     = (const float*)d_in[0];
    const float* v     = (const float*)d_in[1];
    const float* force = (const float*)d_in[2];
    const float* U     = (const float*)d_in[3];
    const float* W     = (const float*)d_in[4];
    const int*   steps = (const int*)d_in[5];

    short* Up = (short*)d_ws;                 // 32768 * 16B = 512 KB
    short* Wp = Up + 32768 * 8;               // 512 KB

    pack_kernel<<<256, 256, 0, stream>>>(U, W, Up, Wp);
    euler_kernel<<<256, 512, 0, stream>>>(x, v, force,
                                          (const short8*)Up, (const short8*)Wp,
                                          steps, (float*)d_out);
}

// Round 3
// 462.192 us; speedup vs baseline: 1.2186x; 1.2186x over previous
//
#include <hip/hip_runtime.h>
#include <hip/hip_bf16.h>

// EulerIntegrator: B=4096, D=1024, R=256, steps=8, dt=0.01
// Persistent per-row-tile kernel: 256 blocks x 16 rows, all steps local.
// GEMM1: P[16x256] = v[16x1024] @ U   (bf16 MFMA 16x16x32)
// GEMM2: G[16x1024] = (P*P)[16x256] @ W
// Round 3: kill the spills. force lives in LDS fp32 (saves 32 VGPRs),
// __launch_bounds__(512,1) lifts the 128-VGPR cap (8 waves = 2/SIMD can use
// up to 256). Register rings + lgkm-only barriers kept from round 2.
// 1 block/CU is deliberate: ILP (rings) over TLP, registers are the scarce
// resource.

#define BB 4096
#define DD 1024
#define RR 256
#define DT 0.01f

typedef __attribute__((ext_vector_type(8))) short short8;   // 8 bf16 = 4 VGPRs
typedef __attribute__((ext_vector_type(4))) float floatx4;  // MFMA acc

// s_waitcnt imm: vmcnt[3:0]|[15:14], expcnt[6:4], lgkmcnt[11:8]
// lgkmcnt(0) only, vmcnt/expcnt unconstrained -> in-flight global loads
// survive the barrier (no vmcnt(0) drain).
#define BARRIER_LGKM() do { \
    __builtin_amdgcn_s_waitcnt(0xC07F); \
    __builtin_amdgcn_s_barrier(); \
} while (0)

static __device__ inline unsigned short f2bf(float f) {
    union { float f; unsigned int u; } c; c.f = f;
    unsigned int u = c.u;
    u += 0x7fffu + ((u >> 16) & 1u);   // round-to-nearest-even
    return (unsigned short)(u >> 16);
}

// Pack U [1024][256] and W [256][1024] (fp32 row-major) into bf16 MFMA
// B-fragment order: dst[(kt*NT + nt)*64 + lane] = 8 bf16, element j =
// M[kt*32 + (lane>>4)*8 + j][nt*16 + (lane&15)].
__global__ void pack_kernel(const float* __restrict__ U, const float* __restrict__ W,
                            short* __restrict__ Up, short* __restrict__ Wp) {
    int t = blockIdx.x * blockDim.x + threadIdx.x;  // 0..65535
    if (t < 32768) {
        int lane = t & 63;
        int nl = lane & 15, kq = lane >> 4;
        int idx = t >> 6;            // kt*16 + nt
        int nt = idx & 15, kt = idx >> 4;
        short8 o;
#pragma unroll
        for (int j = 0; j < 8; j++) {
            int k = kt * 32 + kq * 8 + j;
            int n = nt * 16 + nl;
            o[j] = (short)f2bf(U[k * RR + n]);
        }
        ((short8*)Up)[t] = o;
    } else {
        int t2 = t - 32768;
        int lane = t2 & 63;
        int nl = lane & 15, kq = lane >> 4;
        int idx = t2 >> 6;           // kt*64 + nt
        int nt = idx & 63, kt = idx >> 6;
        short8 o;
#pragma unroll
        for (int j = 0; j < 8; j++) {
            int k = kt * 32 + kq * 8 + j;
            int n = nt * 16 + nl;
            o[j] = (short)f2bf(W[k * DD + n]);
        }
        ((short8*)Wp)[t2] = o;
    }
}

__global__ __launch_bounds__(512, 1)
void euler_kernel(const float* __restrict__ x0,
                  const float* __restrict__ v0,
                  const float* __restrict__ force,
                  const short8* __restrict__ Up,
                  const short8* __restrict__ Wp,
                  const int* __restrict__ steps_p,
                  float* __restrict__ out) {
    __shared__ __align__(16) short v_lds[16][1032];   // 33.0 KB, bf16 v tile
    __shared__ __align__(16) short p2_lds[16][264];   //  8.4 KB, bf16 p^2 tile
    __shared__ __align__(16) float f_lds[16][1028];   // 64.3 KB, fp32 force tile

    const int tid  = threadIdx.x;
    const int wave = tid >> 6;          // 0..7
    const int lane = tid & 63;
    const int nl   = lane & 15;         // M (A) / N (B) / col (C)
    const int quad = lane >> 4;         // 0..3
    const int row0 = blockIdx.x * 16;

    const int steps = steps_p[0];

    // Ownership (matches MFMA C/D layout of GEMM2, 8 tiles/wave):
    // element (tt, r): row = 4*quad + r, col = 128*wave + 16*tt + nl
    float v_reg[8][4], sv[8][4];

#pragma unroll
    for (int tt = 0; tt < 8; tt++) {
        int col = 128 * wave + 16 * tt + nl;
#pragma unroll
        for (int r = 0; r < 4; r++) {
            int row = 4 * quad + r;
            long g = (long)(row0 + row) * DD + col;
            v_reg[tt][r] = v0[g];
            f_lds[row][col] = force[g];
            sv[tt][r] = 0.0f;
            v_lds[row][col] = (short)f2bf(v_reg[tt][r]);
        }
    }

    // -------- GEMM1 B-ring (depth 4) and GEMM2 B-ring (depth 8), regs.
    short8 b0r[4], b1r[4], br[8];

    // GEMM1 prologue for step 0 (loads only touch regs; cross the barrier).
#pragma unroll
    for (int i = 0; i < 4; i++) {
        b0r[i] = Up[(i * 16 + 2 * wave    ) * 64 + lane];
        b1r[i] = Up[(i * 16 + 2 * wave + 1) * 64 + lane];
    }

    BARRIER_LGKM();

    for (int s = 0; s < steps; s++) {
        // ---------------- GEMM1: P = v @ U ; wave computes nt = 2w, 2w+1
        floatx4 acc0 = {0.f, 0.f, 0.f, 0.f};
        floatx4 acc1 = {0.f, 0.f, 0.f, 0.f};
#pragma unroll
        for (int kt = 0; kt < 32; kt++) {
            short8 a = *(const short8*)&v_lds[nl][kt * 32 + quad * 8];
            acc0 = __builtin_amdgcn_mfma_f32_16x16x32_bf16(a, b0r[kt & 3], acc0, 0, 0, 0);
            acc1 = __builtin_amdgcn_mfma_f32_16x16x32_bf16(a, b1r[kt & 3], acc1, 0, 0, 0);
            if (kt < 28) {
                b0r[kt & 3] = Up[((kt + 4) * 16 + 2 * wave    ) * 64 + lane];
                b1r[kt & 3] = Up[((kt + 4) * 16 + 2 * wave + 1) * 64 + lane];
            }
        }

        // GEMM2 prologue (kt=0, tt=0..7) — in flight across the p2 barrier.
#pragma unroll
        for (int j = 0; j < 8; j++)
            br[j] = Wp[(8 * wave + j) * 64 + lane];

        // p^2 epilogue -> LDS (D layout: row = 4*quad + r, col = nt*16 + nl)
#pragma unroll
        for (int r = 0; r < 4; r++) {
            int row = 4 * quad + r;
            float p0 = acc0[r], p1 = acc1[r];
            p2_lds[row][32 * wave + nl]      = (short)f2bf(p0 * p0);
            p2_lds[row][32 * wave + 16 + nl] = (short)f2bf(p1 * p1);
        }
        BARRIER_LGKM();

        // ---------------- GEMM2: G = p2 @ W ; wave computes nt = 8w + tt
        floatx4 acc[8];
#pragma unroll
        for (int tt = 0; tt < 8; tt++) acc[tt] = (floatx4){0.f, 0.f, 0.f, 0.f};
        short8 a2;
#pragma unroll
        for (int f = 0; f < 64; f++) {
            int kt = f >> 3, tt = f & 7;
            if (tt == 0)
                a2 = *(const short8*)&p2_lds[nl][kt * 32 + quad * 8];
            acc[tt] = __builtin_amdgcn_mfma_f32_16x16x32_bf16(a2, br[tt], acc[tt], 0, 0, 0);
            if (f < 56)
                br[tt] = Wp[((kt + 1) * 64 + 8 * wave + tt) * 64 + lane];
        }

        // GEMM1 prologue for next step — in flight across the v barrier.
        // (acc0/acc1 and br are dead here; ring regs are the only adds.)
#pragma unroll
        for (int i = 0; i < 4; i++) {
            b0r[i] = Up[(i * 16 + 2 * wave    ) * 64 + lane];
            b1r[i] = Up[(i * 16 + 2 * wave + 1) * 64 + lane];
        }

        // Euler update epilogue, refresh bf16 v in LDS
#pragma unroll
        for (int tt = 0; tt < 8; tt++) {
            int col = 128 * wave + 16 * tt + nl;
#pragma unroll
            for (int r = 0; r < 4; r++) {
                int row = 4 * quad + r;
                float gma = acc[tt][r];
                float fv  = f_lds[row][col];
                sv[tt][r] += v_reg[tt][r];                       // x accumulates pre-update v
                v_reg[tt][r] += DT * (fv - gma);
                v_lds[row][col] = (short)f2bf(v_reg[tt][r]);
            }
        }
        BARRIER_LGKM();
    }

    // outputs: [cx | cv], cx = x0 + dt * sum(v_t)
#pragma unroll
    for (int tt = 0; tt < 8; tt++) {
        int col = 128 * wave + 16 * tt + nl;
#pragma unroll
        for (int r = 0; r < 4; r++) {
            int row = 4 * quad + r;
            long g = (long)(row0 + row) * DD + col;
            out[g] = x0[g] + DT * sv[tt][r];
            out[(long)BB * DD + g] = v_reg[tt][r];
        }
    }
}

extern "C" void kernel_launch(void* const* d_in, const int* in_sizes, int n_in,
                              void* d_out, int out_size, void* d_ws, size_t ws_size,
                              hipStream_t stream) {
    const float* x     = (const float*)d_in[0];
    const float* v     = (const float*)d_in[1];
    const float* force = (const float*)d_in[2];
    const float* U     = (const float*)d_in[3];
    const float* W     = (const float*)d_in[4];
    const int*   steps = (const int*)d_in[5];

    short* Up = (short*)d_ws;                 // 32768 * 16B = 512 KB
    short* Wp = Up + 32768 * 8;               // 512 KB

    pack_kernel<<<256, 256, 0, stream>>>(U, W, Up, Wp);
    euler_kernel<<<256, 512, 0, stream>>>(x, v, force,
                                          (const short8*)Up, (const short8*)Wp,
                                          steps, (float*)d_out);
}